// Round 1
// 118.033 us; speedup vs baseline: 1.0160x; 1.0160x over previous
//
#include <hip/hip_runtime.h>

// Problem constants
#define HW_   36864      // 192*192
#define WI    192
#define HT    192
#define CIN   128
#define DK    256        // == D_V
#define NH    8
#define DKH   32         // channels per head
// TEMPER = 16 -> scale 1/16 = 0.0625
// Inputs/output are fp32 (established rounds 2-7).

using short4_ = __attribute__((ext_vector_type(4))) short;
using short8  = __attribute__((ext_vector_type(8))) short;
using float4_ = __attribute__((ext_vector_type(4))) float;

static __device__ __forceinline__ float b2f(unsigned short u) {
    union { unsigned int i; float f; } x; x.i = ((unsigned int)u) << 16; return x.f;
}
static __device__ __forceinline__ unsigned short f2b(float f) {
    union { float f; unsigned int i; } x; x.f = f;
    unsigned int r = x.i + 0x7FFFu + ((x.i >> 16) & 1u);   // round-nearest-even
    return (unsigned short)(r >> 16);
}

// ---------------------------------------------------------------------------
// Kernel 1: weights fp32 -> bf16 wqkv[8][96][128] (rows 0-31 q, 32-63 k,
// 64-95 v per head). 384 blocks, r4-verified indexing.  (UNCHANGED)
// ---------------------------------------------------------------------------
__global__ __launch_bounds__(256) void convw_kernel(
    const float* __restrict__ wq,
    const float* __restrict__ wk,
    const float* __restrict__ wv,
    unsigned short* __restrict__ wqkv)
{
    int id = blockIdx.x * 256 + threadIdx.x;   // 98304 = 8*96*128
    int h   = id / 12288;
    int rem = id - h * 12288;
    int r   = rem >> 7;
    int c   = rem & 127;
    const float* __restrict__ s = (r < 32) ? wq : ((r < 64) ? wk : wv);
    wqkv[id] = f2b(s[(h * 32 + (r & 31)) * 128 + c]);
}

// ---------------------------------------------------------------------------
// Kernel 2: fused projection.  (UNCHANGED this round — isolating k3 delta)
// ---------------------------------------------------------------------------
__global__ __launch_bounds__(256) void projfused2_kernel(
    const float* __restrict__ x,               // [128][HW] fp32
    const unsigned short* __restrict__ wqkv,   // [8][96][128] bf16
    unsigned short* __restrict__ vbuf,         // [8][HW][32] bf16
    float* __restrict__ sbuf)                  // [8][HW] fp32
{
    __shared__ unsigned short Sh[96 * 136];    // union: B-tile (64x136) then A-tile (96x136)
    const int px0 = blockIdx.x * 64;
    const int t   = threadIdx.x;
    const int lane = t & 63, wave = t >> 6;
    const int col  = lane & 15, quad = lane >> 4;

    // ---- Stage B: Sh[p][c] = bf16(x[c][px0+p]), 64 px x 128 ch ----
    #pragma unroll 4
    for (int i = 0; i < 32; ++i) {
        int id = i * 256 + t;
        int c = id >> 6, p = id & 63;
        Sh[p * 136 + c] = f2b(x[c * HW_ + px0 + p]);
    }
    __syncthreads();

    // ---- B fragments into registers ----
    short8 bfrag[4];
    {
        int n = wave * 16 + col;
        #pragma unroll
        for (int kt = 0; kt < 4; ++kt)
            bfrag[kt] = *(const short8*)&Sh[n * 136 + kt * 32 + quad * 8];
    }

    for (int head = 0; head < 8; ++head) {
        __syncthreads();                       // all reads of Sh done
        const unsigned short* __restrict__ Ag = wqkv + head * 96 * 128;
        #pragma unroll
        for (int i = 0; i < 6; ++i) {
            int id = i * 256 + t;              // 96*16 = 1536 16B chunks
            int row = id >> 4, c8 = id & 15;
            *(short8*)&Sh[row * 136 + c8 * 8] = *(const short8*)&Ag[row * 128 + c8 * 8];
        }
        __syncthreads();

        float4_ acc[6];
        #pragma unroll
        for (int mt = 0; mt < 6; ++mt)
            acc[mt] = (float4_){0.f, 0.f, 0.f, 0.f};

        #pragma unroll
        for (int mt = 0; mt < 6; ++mt) {
            #pragma unroll
            for (int kt = 0; kt < 4; ++kt) {
                short8 a = *(const short8*)&Sh[(mt * 16 + col) * 136 + kt * 32 + quad * 8];
                acc[mt] = __builtin_amdgcn_mfma_f32_16x16x32_bf16(a, bfrag[kt], acc[mt], 0, 0, 0);
            }
        }

        // ---- Epilogue (r4-verified). C/D: col = pixel, row = quad*4+reg ----
        int px = px0 + wave * 16 + col;
        float s = 0.f;
        #pragma unroll
        for (int reg = 0; reg < 4; ++reg)
            s += acc[0][reg] * acc[2][reg]
               + acc[1][reg] * acc[3][reg];
        s += __shfl_xor(s, 16, 64);
        s += __shfl_xor(s, 32, 64);
        if (quad == 0) sbuf[head * HW_ + px] = s;
        unsigned short* vp = vbuf + ((size_t)head * HW_ + px) * 32;
        short4_ v0, v1;
        #pragma unroll
        for (int reg = 0; reg < 4; ++reg) {
            v0[reg] = (short)f2b(acc[4][reg]);
            v1[reg] = (short)f2b(acc[5][reg]);
        }
        *(short4_*)&vp[quad * 4]      = v0;
        *(short4_*)&vp[16 + quad * 4] = v1;
    }
}

// ---------------------------------------------------------------------------
// Kernel 3 (REWRITTEN): regional softmax + weighted 3x3 gather with 2D
// 16x4 pixel tiles and LDS halo staging.
//   - Block = 64 px (16 wide x 4 tall) x 1 head, 256 thr (px x 4 ch-groups).
//   - Stage the 18x6 halo of V (bf16, 6.9 KB) + scores (432 B) into LDS
//     once: 5.3x less cache-side read traffic, ~8x fewer VMEM ops than the
//     per-thread 9-neighbor global gather; kills the cross-XCD L2 misses
//     the 1D strip tiling caused (row neighbors were tiles +-3 -> other XCDs).
//   - Softmax math is IDENTICAL to the verified r4/r6/r7 version (same
//     values, same op order; OOB lanes: val=0 participates in max, e^(0-m)
//     in sum, weight zeroed after normalize). Clamped staging only feeds
//     lanes whose weight is zeroed, and vbuf data is finite (no NaN*0).
//   - Output: d-major fp32 via LDS transpose (stride 65, conflict-free
//     readout); writes are 32B chunks forming full 64B sectors (x0 % 16 == 0).
// ---------------------------------------------------------------------------
__global__ __launch_bounds__(256) void attn_kernel(
    const unsigned short* __restrict__ vbuf,  // [8][HW][32] bf16
    const float* __restrict__ sbuf,           // [8][HW]
    float* __restrict__ out)                  // [256][HW] fp32
{
    __shared__ unsigned short Vh[6][18][32];  // 6912 B halo V tile
    __shared__ float Ssc[6][18];              // 432 B halo scores
    __shared__ float tr[32][65];              // 8320 B transpose buffer

    const int b    = blockIdx.x;              // 4608 = 576 px-tiles * 8 heads
    const int tile = b % 576;
    const int head = b / 576;
    const int t    = threadIdx.x;
    const int ty = tile / 12, tx = tile - ty * 12;   // 12 x 48 tile grid
    const int y0 = ty * 4, x0 = tx * 16;

    const unsigned short* __restrict__ vb = vbuf + (size_t)head * HW_ * 32;
    const float* __restrict__ Sg = sbuf + head * HW_;

    // ---- stage halo: 108 cells x 64B = 432 16B chunks ----
    for (int id = t; id < 432; id += 256) {
        int cell = id >> 2, q = id & 3;
        int hy = cell / 18, hx = cell - hy * 18;
        int gy = y0 - 1 + hy; gy = gy < 0 ? 0 : (gy > HT - 1 ? HT - 1 : gy);
        int gx = x0 - 1 + hx; gx = gx < 0 ? 0 : (gx > WI - 1 ? WI - 1 : gx);
        *(short8*)&Vh[hy][hx][q * 8] =
            *(const short8*)&vb[((size_t)(gy * WI + gx)) * 32 + q * 8];
    }
    if (t < 108) {
        int hy = t / 18, hx = t - hy * 18;
        int gy = y0 - 1 + hy; gy = gy < 0 ? 0 : (gy > HT - 1 ? HT - 1 : gy);
        int gx = x0 - 1 + hx; gx = gx < 0 ? 0 : (gx > WI - 1 ? WI - 1 : gx);
        Ssc[hy][hx] = Sg[gy * WI + gx];
    }
    __syncthreads();

    // ---- per-pixel softmax over the 9 region slots (identical math) ----
    const int pxl = t >> 2;                   // 0..63
    const int cg  = t & 3;                    // channel group (8 ch)
    const int ly  = pxl >> 4, lx = pxl & 15;  // 4 x 16 tile coords
    const int y   = y0 + ly, xx = x0 + lx;

    float w[9];
    float m = -1e30f;
    #pragma unroll
    for (int r = 0; r < 9; ++r) {
        int dy = r / 3 - 1, dx = r % 3 - 1;
        int ny = y + dy, nx = xx + dx;
        bool inb = (ny >= 0) && (ny < HT) && (nx >= 0) && (nx < WI);
        float val = inb ? (Ssc[ly + dy + 1][lx + dx + 1] * 0.0625f) : 0.0f;
        w[r] = val;
        m = fmaxf(m, val);
    }
    float wsum = 0.f;
    #pragma unroll
    for (int r = 0; r < 9; ++r) {
        float e = __expf(w[r] - m);
        w[r] = e;
        wsum += e;
    }
    float inv = 1.0f / wsum;
    #pragma unroll
    for (int r = 0; r < 9; ++r) {
        int dy = r / 3 - 1, dx = r % 3 - 1;
        int ny = y + dy, nx = xx + dx;
        bool inb = (ny >= 0) && (ny < HT) && (nx >= 0) && (nx < WI);
        w[r] = inb ? (w[r] * inv) : 0.0f;
    }

    // ---- weighted gather from LDS halo ----
    float acc[8] = {0.f, 0.f, 0.f, 0.f, 0.f, 0.f, 0.f, 0.f};
    #pragma unroll
    for (int r = 0; r < 9; ++r) {
        int dy = r / 3 - 1, dx = r % 3 - 1;
        short8 v8 = *(const short8*)&Vh[ly + dy + 1][lx + dx + 1][cg * 8];
        #pragma unroll
        for (int j = 0; j < 8; ++j)
            acc[j] = fmaf(w[r], b2f((unsigned short)v8[j]), acc[j]);
    }
    #pragma unroll
    for (int j = 0; j < 8; ++j)
        tr[cg * 8 + j][pxl] = acc[j];
    __syncthreads();

    // ---- write-out: thread t -> channel ch = t>>3, row ly2, 8-px half ----
    const int ch   = t >> 3;
    const int ly2  = (t >> 1) & 3;
    const int half = t & 1;
    float4_ o0, o1;
    #pragma unroll
    for (int j = 0; j < 4; ++j) {
        o0[j] = tr[ch][ly2 * 16 + half * 8 + j];
        o1[j] = tr[ch][ly2 * 16 + half * 8 + 4 + j];
    }
    float* o = out + (size_t)(head * DKH + ch) * HW_ + (y0 + ly2) * WI + x0 + half * 8;
    *(float4_*)&o[0] = o0;
    *(float4_*)&o[4] = o1;
}

// ---------------------------------------------------------------------------
// Workspace layout:
//   [0, 196608)              wqkv : 8*96*128 bf16
//   [196608, 19071104)       vbuf : 8*36864*32 bf16 (pixel-major)
//   [19071104, 20250752)     sbuf : 8*36864 fp32
// ---------------------------------------------------------------------------
extern "C" void kernel_launch(void* const* d_in, const int* in_sizes, int n_in,
                              void* d_out, int out_size, void* d_ws, size_t ws_size,
                              hipStream_t stream) {
    const float* x  = (const float*)d_in[0];
    const float* wq = (const float*)d_in[1];
    const float* wk = (const float*)d_in[2];
    const float* wv = (const float*)d_in[3];

    char* ws = (char*)d_ws;
    unsigned short* wqkv = (unsigned short*)ws;
    unsigned short* vbuf = (unsigned short*)(ws + 196608);
    float*          sbuf = (float*)(ws + 19071104);

    convw_kernel<<<384, 256, 0, stream>>>(wq, wk, wv, wqkv);
    projfused2_kernel<<<576, 256, 0, stream>>>(x, wqkv, vbuf, sbuf);
    attn_kernel<<<4608, 256, 0, stream>>>(vbuf, sbuf, (float*)d_out);
}

// Round 2
// 109.176 us; speedup vs baseline: 1.0985x; 1.0811x over previous
//
#include <hip/hip_runtime.h>

// Problem constants
#define HW_   36864      // 192*192
#define WI    192
#define HT    192
#define CIN   128
#define DK    256        // == D_V
#define NH    8
#define DKH   32         // channels per head
// TEMPER = 16 -> scale 1/16 = 0.0625
// Inputs/output are fp32 (established rounds 2-7).

using short4_ = __attribute__((ext_vector_type(4))) short;
using short8  = __attribute__((ext_vector_type(8))) short;
using float4_ = __attribute__((ext_vector_type(4))) float;

static __device__ __forceinline__ float b2f(unsigned short u) {
    union { unsigned int i; float f; } x; x.i = ((unsigned int)u) << 16; return x.f;
}
static __device__ __forceinline__ unsigned short f2b(float f) {
    union { float f; unsigned int i; } x; x.f = f;
    unsigned int r = x.i + 0x7FFFu + ((x.i >> 16) & 1u);   // round-nearest-even
    return (unsigned short)(r >> 16);
}

// ---------------------------------------------------------------------------
// Kernel 1: weights fp32 -> bf16 wqkv[8][96][128], NEW interleaved row
// layout per head:
//   rows  0-15 : q[ 0:16]   rows 16-31 : k[ 0:16]   rows 32-47 : v[ 0:16]
//   rows 48-63 : q[16:32]   rows 64-79 : k[16:32]   rows 80-95 : v[16:32]
// This keeps the q*k dot-product pairing intra-wave under k2's 2x2 wave
// decomposition (wave wm owns dk/dv range [wm*16, wm*16+16)).
// ---------------------------------------------------------------------------
__global__ __launch_bounds__(256) void convw_kernel(
    const float* __restrict__ wq,
    const float* __restrict__ wk,
    const float* __restrict__ wv,
    unsigned short* __restrict__ wqkv)
{
    int id = blockIdx.x * 256 + threadIdx.x;   // 98304 = 8*96*128
    int h   = id / 12288;
    int rem = id - h * 12288;
    int r   = rem >> 7;                        // 0..95
    int c   = rem & 127;
    int g   = r >> 4;                          // 0..5
    int gm  = g % 3;                           // 0=q 1=k 2=v
    int rr  = ((g >= 3) ? 16 : 0) + (r & 15);  // channel within head half
    const float* __restrict__ s = (gm == 0) ? wq : ((gm == 1) ? wk : wv);
    wqkv[id] = f2b(s[(h * 32 + rr) * 128 + c]);
}

// ---------------------------------------------------------------------------
// Kernel 2 (RESTRUCTURED): fused projection with
//   - 2x2 wave split: wm = wave>>1 owns 48 A-rows (q/k/v chunk for dk half
//     wm*16..wm*16+16), wn = wave&1 owns 32 of the 64 pixels. Each A
//     fragment read feeds 2 MFMAs -> A ds_read_b128 traffic HALVED
//     (12/lane/head vs 24).
//   - Double-buffered A staging: head h+1 staged while head h computes;
//     ONE barrier per head (was 2), staging latency hidden under MFMA.
//   - q*k partial dot per wm half -> tiny double-buffered sP LDS buffer,
//     summed after the per-head barrier.
// MFMA fragment pattern (stride 136) and C/D interpretation (col=pixel,
// row=quad*4+reg) are the r3/r4-verified ones, unchanged.
// LDS = 53.2 KB -> 3 blocks/CU.
// ---------------------------------------------------------------------------
__global__ __launch_bounds__(256) void projfused3_kernel(
    const float* __restrict__ x,               // [128][HW] fp32
    const unsigned short* __restrict__ wqkv,   // [8][96][128] bf16 (interleaved rows)
    unsigned short* __restrict__ vbuf,         // [8][HW][32] bf16
    float* __restrict__ sbuf)                  // [8][HW] fp32
{
    __shared__ unsigned short ShA[2][96 * 136];  // A double buffer (B-tile aliases ShA[0])
    __shared__ float sP[2][2][64];               // [parity][wm][px] q.k partials

    const int px0 = blockIdx.x * 64;
    const int t   = threadIdx.x;
    const int lane = t & 63, wave = t >> 6;
    const int col  = lane & 15, quad = lane >> 4;
    const int wm   = wave >> 1, wn = wave & 1;

    // ---- Stage B into ShA[0] low region: Bs[p][c] = bf16(x[c][px0+p]) ----
    unsigned short* Bs = &ShA[0][0];
    #pragma unroll 4
    for (int i = 0; i < 32; ++i) {
        int id = i * 256 + t;
        int c = id >> 6, p = id & 63;
        Bs[p * 136 + c] = f2b(x[c * HW_ + px0 + p]);
    }
    __syncthreads();

    // ---- B fragments into registers: lane holds pixel n = wn*32+nt*16+col ----
    short8 bfrag[2][4];
    #pragma unroll
    for (int nt = 0; nt < 2; ++nt) {
        int n = wn * 32 + nt * 16 + col;
        #pragma unroll
        for (int kt = 0; kt < 4; ++kt)
            bfrag[nt][kt] = *(const short8*)&Bs[n * 136 + kt * 32 + quad * 8];
    }
    __syncthreads();                           // B reads done; ShA[0] reusable

    // ---- Stage A head 0 into ShA[0] ----
    {
        const unsigned short* __restrict__ Ag = wqkv;
        #pragma unroll
        for (int i = 0; i < 6; ++i) {
            int id = i * 256 + t;              // 1536 16B chunks
            int row = id >> 4, c8 = id & 15;
            *(short8*)&ShA[0][row * 136 + c8 * 8] = *(const short8*)&Ag[row * 128 + c8 * 8];
        }
    }
    __syncthreads();

    for (int head = 0; head < 8; ++head) {
        // ---- prefetch head+1 into the other buffer (overlaps compute) ----
        if (head < 7) {
            const unsigned short* __restrict__ Ag = wqkv + (head + 1) * 96 * 128;
            unsigned short* __restrict__ Ad = &ShA[(head + 1) & 1][0];
            #pragma unroll
            for (int i = 0; i < 6; ++i) {
                int id = i * 256 + t;
                int row = id >> 4, c8 = id & 15;
                *(short8*)&Ad[row * 136 + c8 * 8] = *(const short8*)&Ag[row * 128 + c8 * 8];
            }
        }
        const unsigned short* __restrict__ As = &ShA[head & 1][0];

        float4_ acc[3][2];
        #pragma unroll
        for (int mt = 0; mt < 3; ++mt) {
            acc[mt][0] = (float4_){0.f, 0.f, 0.f, 0.f};
            acc[mt][1] = (float4_){0.f, 0.f, 0.f, 0.f};
        }

        // mt: 0=q-chunk 1=k-chunk 2=v-chunk of this wm half
        #pragma unroll
        for (int mt = 0; mt < 3; ++mt) {
            #pragma unroll
            for (int kt = 0; kt < 4; ++kt) {
                short8 a = *(const short8*)&As[(wm * 48 + mt * 16 + col) * 136 + kt * 32 + quad * 8];
                acc[mt][0] = __builtin_amdgcn_mfma_f32_16x16x32_bf16(a, bfrag[0][kt], acc[mt][0], 0, 0, 0);
                acc[mt][1] = __builtin_amdgcn_mfma_f32_16x16x32_bf16(a, bfrag[1][kt], acc[mt][1], 0, 0, 0);
            }
        }

        // ---- Epilogue. C/D: col = pixel, row(channel) = quad*4+reg ----
        #pragma unroll
        for (int nt = 0; nt < 2; ++nt) {
            int px = px0 + wn * 32 + nt * 16 + col;
            float s = 0.f;
            #pragma unroll
            for (int reg = 0; reg < 4; ++reg)
                s += acc[0][nt][reg] * acc[1][nt][reg];   // q.k partial (16 dk of this wm)
            s += __shfl_xor(s, 16, 64);
            s += __shfl_xor(s, 32, 64);
            if (quad == 0) sP[head & 1][wm][wn * 32 + nt * 16 + col] = s;
            // v output channels dv = wm*16 + quad*4 + reg
            unsigned short* vp = vbuf + ((size_t)head * HW_ + px) * 32;
            short4_ v0;
            #pragma unroll
            for (int reg = 0; reg < 4; ++reg)
                v0[reg] = (short)f2b(acc[2][nt][reg]);
            *(short4_*)&vp[wm * 16 + quad * 4] = v0;
        }

        __syncthreads();   // (a) sP visible (b) prefetch h+1 landed (c) As reads done

        if (t < 64)
            sbuf[head * HW_ + px0 + t] = sP[head & 1][0][t] + sP[head & 1][1][t];
    }
}

// ---------------------------------------------------------------------------
// Kernel 3: regional softmax + weighted 3x3 gather with 2D 16x4 pixel tiles
// and LDS halo staging.  (UNCHANGED this round — isolating k2 delta)
// ---------------------------------------------------------------------------
__global__ __launch_bounds__(256) void attn_kernel(
    const unsigned short* __restrict__ vbuf,  // [8][HW][32] bf16
    const float* __restrict__ sbuf,           // [8][HW]
    float* __restrict__ out)                  // [256][HW] fp32
{
    __shared__ unsigned short Vh[6][18][32];  // 6912 B halo V tile
    __shared__ float Ssc[6][18];              // 432 B halo scores
    __shared__ float tr[32][65];              // 8320 B transpose buffer

    const int b    = blockIdx.x;              // 4608 = 576 px-tiles * 8 heads
    const int tile = b % 576;
    const int head = b / 576;
    const int t    = threadIdx.x;
    const int ty = tile / 12, tx = tile - ty * 12;   // 12 x 48 tile grid
    const int y0 = ty * 4, x0 = tx * 16;

    const unsigned short* __restrict__ vb = vbuf + (size_t)head * HW_ * 32;
    const float* __restrict__ Sg = sbuf + head * HW_;

    // ---- stage halo: 108 cells x 64B = 432 16B chunks ----
    for (int id = t; id < 432; id += 256) {
        int cell = id >> 2, q = id & 3;
        int hy = cell / 18, hx = cell - hy * 18;
        int gy = y0 - 1 + hy; gy = gy < 0 ? 0 : (gy > HT - 1 ? HT - 1 : gy);
        int gx = x0 - 1 + hx; gx = gx < 0 ? 0 : (gx > WI - 1 ? WI - 1 : gx);
        *(short8*)&Vh[hy][hx][q * 8] =
            *(const short8*)&vb[((size_t)(gy * WI + gx)) * 32 + q * 8];
    }
    if (t < 108) {
        int hy = t / 18, hx = t - hy * 18;
        int gy = y0 - 1 + hy; gy = gy < 0 ? 0 : (gy > HT - 1 ? HT - 1 : gy);
        int gx = x0 - 1 + hx; gx = gx < 0 ? 0 : (gx > WI - 1 ? WI - 1 : gx);
        Ssc[hy][hx] = Sg[gy * WI + gx];
    }
    __syncthreads();

    // ---- per-pixel softmax over the 9 region slots (identical math) ----
    const int pxl = t >> 2;                   // 0..63
    const int cg  = t & 3;                    // channel group (8 ch)
    const int ly  = pxl >> 4, lx = pxl & 15;  // 4 x 16 tile coords
    const int y   = y0 + ly, xx = x0 + lx;

    float w[9];
    float m = -1e30f;
    #pragma unroll
    for (int r = 0; r < 9; ++r) {
        int dy = r / 3 - 1, dx = r % 3 - 1;
        int ny = y + dy, nx = xx + dx;
        bool inb = (ny >= 0) && (ny < HT) && (nx >= 0) && (nx < WI);
        float val = inb ? (Ssc[ly + dy + 1][lx + dx + 1] * 0.0625f) : 0.0f;
        w[r] = val;
        m = fmaxf(m, val);
    }
    float wsum = 0.f;
    #pragma unroll
    for (int r = 0; r < 9; ++r) {
        float e = __expf(w[r] - m);
        w[r] = e;
        wsum += e;
    }
    float inv = 1.0f / wsum;
    #pragma unroll
    for (int r = 0; r < 9; ++r) {
        int dy = r / 3 - 1, dx = r % 3 - 1;
        int ny = y + dy, nx = xx + dx;
        bool inb = (ny >= 0) && (ny < HT) && (nx >= 0) && (nx < WI);
        w[r] = inb ? (w[r] * inv) : 0.0f;
    }

    // ---- weighted gather from LDS halo ----
    float acc[8] = {0.f, 0.f, 0.f, 0.f, 0.f, 0.f, 0.f, 0.f};
    #pragma unroll
    for (int r = 0; r < 9; ++r) {
        int dy = r / 3 - 1, dx = r % 3 - 1;
        short8 v8 = *(const short8*)&Vh[ly + dy + 1][lx + dx + 1][cg * 8];
        #pragma unroll
        for (int j = 0; j < 8; ++j)
            acc[j] = fmaf(w[r], b2f((unsigned short)v8[j]), acc[j]);
    }
    #pragma unroll
    for (int j = 0; j < 8; ++j)
        tr[cg * 8 + j][pxl] = acc[j];
    __syncthreads();

    // ---- write-out: thread t -> channel ch = t>>3, row ly2, 8-px half ----
    const int ch   = t >> 3;
    const int ly2  = (t >> 1) & 3;
    const int half = t & 1;
    float4_ o0, o1;
    #pragma unroll
    for (int j = 0; j < 4; ++j) {
        o0[j] = tr[ch][ly2 * 16 + half * 8 + j];
        o1[j] = tr[ch][ly2 * 16 + half * 8 + 4 + j];
    }
    float* o = out + (size_t)(head * DKH + ch) * HW_ + (y0 + ly2) * WI + x0 + half * 8;
    *(float4_*)&o[0] = o0;
    *(float4_*)&o[4] = o1;
}

// ---------------------------------------------------------------------------
// Workspace layout:
//   [0, 196608)              wqkv : 8*96*128 bf16
//   [196608, 19071104)       vbuf : 8*36864*32 bf16 (pixel-major)
//   [19071104, 20250752)     sbuf : 8*36864 fp32
// ---------------------------------------------------------------------------
extern "C" void kernel_launch(void* const* d_in, const int* in_sizes, int n_in,
                              void* d_out, int out_size, void* d_ws, size_t ws_size,
                              hipStream_t stream) {
    const float* x  = (const float*)d_in[0];
    const float* wq = (const float*)d_in[1];
    const float* wk = (const float*)d_in[2];
    const float* wv = (const float*)d_in[3];

    char* ws = (char*)d_ws;
    unsigned short* wqkv = (unsigned short*)ws;
    unsigned short* vbuf = (unsigned short*)(ws + 196608);
    float*          sbuf = (float*)(ws + 19071104);

    convw_kernel<<<384, 256, 0, stream>>>(wq, wk, wv, wqkv);
    projfused3_kernel<<<576, 256, 0, stream>>>(x, wqkv, vbuf, sbuf);
    attn_kernel<<<4608, 256, 0, stream>>>(vbuf, sbuf, (float*)d_out);
}

// Round 3
// 109.086 us; speedup vs baseline: 1.0994x; 1.0008x over previous
//
#include <hip/hip_runtime.h>

// Problem constants
#define HW_   36864      // 192*192
#define WI    192
#define HT    192
#define CIN   128
#define DK    256        // == D_V
#define NH    8
#define DKH   32         // channels per head
// TEMPER = 16 -> scale 1/16 = 0.0625
// Inputs/output are fp32 (established rounds 2-7).

using short4_ = __attribute__((ext_vector_type(4))) short;
using short8  = __attribute__((ext_vector_type(8))) short;
using float4_ = __attribute__((ext_vector_type(4))) float;

static __device__ __forceinline__ float b2f(unsigned short u) {
    union { unsigned int i; float f; } x; x.i = ((unsigned int)u) << 16; return x.f;
}
static __device__ __forceinline__ unsigned short f2b(float f) {
    union { float f; unsigned int i; } x; x.f = f;
    unsigned int r = x.i + 0x7FFFu + ((x.i >> 16) & 1u);   // round-nearest-even
    return (unsigned short)(r >> 16);
}

// ---------------------------------------------------------------------------
// Kernel 1: weights fp32 -> bf16 wqkv[8][96][128], interleaved row layout
// per head (verified r1 of this session):
//   rows  0-15 : q[ 0:16]   rows 16-31 : k[ 0:16]   rows 32-47 : v[ 0:16]
//   rows 48-63 : q[16:32]   rows 64-79 : k[16:32]   rows 80-95 : v[16:32]
// (UNCHANGED)
// ---------------------------------------------------------------------------
__global__ __launch_bounds__(256) void convw_kernel(
    const float* __restrict__ wq,
    const float* __restrict__ wk,
    const float* __restrict__ wv,
    unsigned short* __restrict__ wqkv)
{
    int id = blockIdx.x * 256 + threadIdx.x;   // 98304 = 8*96*128
    int h   = id / 12288;
    int rem = id - h * 12288;
    int r   = rem >> 7;                        // 0..95
    int c   = rem & 127;
    int g   = r >> 4;                          // 0..5
    int gm  = g % 3;                           // 0=q 1=k 2=v
    int rr  = ((g >= 3) ? 16 : 0) + (r & 15);  // channel within head half
    const float* __restrict__ s = (gm == 0) ? wq : ((gm == 1) ? wk : wv);
    wqkv[id] = f2b(s[(h * 32 + rr) * 128 + c]);
}

// ---------------------------------------------------------------------------
// Kernel 2: fused projection, 2x2 wave split + double-buffered A staging
// (verified r2 of this session, -8.9 us).  (UNCHANGED)
// ---------------------------------------------------------------------------
__global__ __launch_bounds__(256) void projfused3_kernel(
    const float* __restrict__ x,               // [128][HW] fp32
    const unsigned short* __restrict__ wqkv,   // [8][96][128] bf16 (interleaved rows)
    unsigned short* __restrict__ vbuf,         // [8][HW][32] bf16
    float* __restrict__ sbuf)                  // [8][HW] fp32
{
    __shared__ unsigned short ShA[2][96 * 136];  // A double buffer (B-tile aliases ShA[0])
    __shared__ float sP[2][2][64];               // [parity][wm][px] q.k partials

    const int px0 = blockIdx.x * 64;
    const int t   = threadIdx.x;
    const int lane = t & 63, wave = t >> 6;
    const int col  = lane & 15, quad = lane >> 4;
    const int wm   = wave >> 1, wn = wave & 1;

    // ---- Stage B into ShA[0] low region: Bs[p][c] = bf16(x[c][px0+p]) ----
    unsigned short* Bs = &ShA[0][0];
    #pragma unroll 4
    for (int i = 0; i < 32; ++i) {
        int id = i * 256 + t;
        int c = id >> 6, p = id & 63;
        Bs[p * 136 + c] = f2b(x[c * HW_ + px0 + p]);
    }
    __syncthreads();

    // ---- B fragments into registers: lane holds pixel n = wn*32+nt*16+col ----
    short8 bfrag[2][4];
    #pragma unroll
    for (int nt = 0; nt < 2; ++nt) {
        int n = wn * 32 + nt * 16 + col;
        #pragma unroll
        for (int kt = 0; kt < 4; ++kt)
            bfrag[nt][kt] = *(const short8*)&Bs[n * 136 + kt * 32 + quad * 8];
    }
    __syncthreads();                           // B reads done; ShA[0] reusable

    // ---- Stage A head 0 into ShA[0] ----
    {
        const unsigned short* __restrict__ Ag = wqkv;
        #pragma unroll
        for (int i = 0; i < 6; ++i) {
            int id = i * 256 + t;              // 1536 16B chunks
            int row = id >> 4, c8 = id & 15;
            *(short8*)&ShA[0][row * 136 + c8 * 8] = *(const short8*)&Ag[row * 128 + c8 * 8];
        }
    }
    __syncthreads();

    for (int head = 0; head < 8; ++head) {
        // ---- prefetch head+1 into the other buffer (overlaps compute) ----
        if (head < 7) {
            const unsigned short* __restrict__ Ag = wqkv + (head + 1) * 96 * 128;
            unsigned short* __restrict__ Ad = &ShA[(head + 1) & 1][0];
            #pragma unroll
            for (int i = 0; i < 6; ++i) {
                int id = i * 256 + t;
                int row = id >> 4, c8 = id & 15;
                *(short8*)&Ad[row * 136 + c8 * 8] = *(const short8*)&Ag[row * 128 + c8 * 8];
            }
        }
        const unsigned short* __restrict__ As = &ShA[head & 1][0];

        float4_ acc[3][2];
        #pragma unroll
        for (int mt = 0; mt < 3; ++mt) {
            acc[mt][0] = (float4_){0.f, 0.f, 0.f, 0.f};
            acc[mt][1] = (float4_){0.f, 0.f, 0.f, 0.f};
        }

        // mt: 0=q-chunk 1=k-chunk 2=v-chunk of this wm half
        #pragma unroll
        for (int mt = 0; mt < 3; ++mt) {
            #pragma unroll
            for (int kt = 0; kt < 4; ++kt) {
                short8 a = *(const short8*)&As[(wm * 48 + mt * 16 + col) * 136 + kt * 32 + quad * 8];
                acc[mt][0] = __builtin_amdgcn_mfma_f32_16x16x32_bf16(a, bfrag[0][kt], acc[mt][0], 0, 0, 0);
                acc[mt][1] = __builtin_amdgcn_mfma_f32_16x16x32_bf16(a, bfrag[1][kt], acc[mt][1], 0, 0, 0);
            }
        }

        // ---- Epilogue. C/D: col = pixel, row(channel) = quad*4+reg ----
        #pragma unroll
        for (int nt = 0; nt < 2; ++nt) {
            int px = px0 + wn * 32 + nt * 16 + col;
            float s = 0.f;
            #pragma unroll
            for (int reg = 0; reg < 4; ++reg)
                s += acc[0][nt][reg] * acc[1][nt][reg];   // q.k partial (16 dk of this wm)
            s += __shfl_xor(s, 16, 64);
            s += __shfl_xor(s, 32, 64);
            if (quad == 0) sP[head & 1][wm][wn * 32 + nt * 16 + col] = s;
            // v output channels dv = wm*16 + quad*4 + reg
            unsigned short* vp = vbuf + ((size_t)head * HW_ + px) * 32;
            short4_ v0;
            #pragma unroll
            for (int reg = 0; reg < 4; ++reg)
                v0[reg] = (short)f2b(acc[2][nt][reg]);
            *(short4_*)&vp[wm * 16 + quad * 4] = v0;
        }

        __syncthreads();   // (a) sP visible (b) prefetch h+1 landed (c) As reads done

        if (t < 64)
            sbuf[head * HW_ + px0 + t] = sP[head & 1][0][t] + sP[head & 1][1][t];
    }
}

// ---------------------------------------------------------------------------
// Kernel 3 (RETILED): 16x8 pixel tiles (128 out px/block), halo 18x10.
//   - Halo overhead 1.69x -> 1.41x; block count 4608 -> 2304.
//   - XCD-head swizzle: wg = (b&7)*288 + b/8 maps each head to one XCD
//     (2304 % 8 == 0, bijective); a head's vbuf slice (2.36 MB) fits the
//     4 MB per-XCD L2 -> halo re-reads become L2 hits.
//   - Thread = 1 px x 16 ch (2 threads/px); softmax math bit-identical to
//     the verified r4/r6/r7 version (same op order, OOB zeroing after
//     normalize; clamped staging only feeds zero-weight lanes).
//   - Write-out: two 64-px halves through the verified tr[32][65]
//     transpose (identical per-thread write shape).
// LDS = 20.6 KB -> 7 blocks/CU.
// ---------------------------------------------------------------------------
__global__ __launch_bounds__(256) void attn_kernel(
    const unsigned short* __restrict__ vbuf,  // [8][HW][32] bf16
    const float* __restrict__ sbuf,           // [8][HW]
    float* __restrict__ out)                  // [256][HW] fp32
{
    __shared__ unsigned short Vh[10][18][32]; // 11.25 KB halo V tile
    __shared__ float Ssc[10][18];             // 720 B halo scores
    __shared__ float tr[32][65];              // 8.3 KB transpose buffer

    const int b    = blockIdx.x;              // 2304 = 8 heads * 288 tiles
    const int wg   = (b & 7) * 288 + (b >> 3);   // XCD-head swizzle
    const int head = wg / 288;
    const int tile = wg - head * 288;
    const int t    = threadIdx.x;
    const int ty = tile / 12, tx = tile - ty * 12;   // 12 x 24 tile grid
    const int y0 = ty * 8, x0 = tx * 16;

    const unsigned short* __restrict__ vb = vbuf + (size_t)head * HW_ * 32;
    const float* __restrict__ Sg = sbuf + head * HW_;

    // ---- stage halo V: 180 cells x 64B = 720 16B chunks ----
    for (int id = t; id < 720; id += 256) {
        int cell = id >> 2, q = id & 3;
        int hy = cell / 18, hx = cell - hy * 18;
        int gy = y0 - 1 + hy; gy = gy < 0 ? 0 : (gy > HT - 1 ? HT - 1 : gy);
        int gx = x0 - 1 + hx; gx = gx < 0 ? 0 : (gx > WI - 1 ? WI - 1 : gx);
        *(short8*)&Vh[hy][hx][q * 8] =
            *(const short8*)&vb[((size_t)(gy * WI + gx)) * 32 + q * 8];
    }
    if (t < 180) {
        int hy = t / 18, hx = t - hy * 18;
        int gy = y0 - 1 + hy; gy = gy < 0 ? 0 : (gy > HT - 1 ? HT - 1 : gy);
        int gx = x0 - 1 + hx; gx = gx < 0 ? 0 : (gx > WI - 1 ? WI - 1 : gx);
        Ssc[hy][hx] = Sg[gy * WI + gx];
    }
    __syncthreads();

    // ---- per-pixel softmax over the 9 region slots (identical math) ----
    const int pxl = t >> 1;                   // 0..127
    const int hg  = t & 1;                    // 16-channel half
    const int ly  = pxl >> 4, lx = pxl & 15;  // 16 x 8 tile coords
    const int y   = y0 + ly, xx = x0 + lx;

    float w[9];
    float m = -1e30f;
    #pragma unroll
    for (int r = 0; r < 9; ++r) {
        int dy = r / 3 - 1, dx = r % 3 - 1;
        int ny = y + dy, nx = xx + dx;
        bool inb = (ny >= 0) && (ny < HT) && (nx >= 0) && (nx < WI);
        float val = inb ? (Ssc[ly + dy + 1][lx + dx + 1] * 0.0625f) : 0.0f;
        w[r] = val;
        m = fmaxf(m, val);
    }
    float wsum = 0.f;
    #pragma unroll
    for (int r = 0; r < 9; ++r) {
        float e = __expf(w[r] - m);
        w[r] = e;
        wsum += e;
    }
    float inv = 1.0f / wsum;
    #pragma unroll
    for (int r = 0; r < 9; ++r) {
        int dy = r / 3 - 1, dx = r % 3 - 1;
        int ny = y + dy, nx = xx + dx;
        bool inb = (ny >= 0) && (ny < HT) && (nx >= 0) && (nx < WI);
        w[r] = inb ? (w[r] * inv) : 0.0f;
    }

    // ---- weighted gather from LDS halo: 16 channels per thread ----
    float acc[16];
    #pragma unroll
    for (int j = 0; j < 16; ++j) acc[j] = 0.f;
    #pragma unroll
    for (int r = 0; r < 9; ++r) {
        int dy = r / 3 - 1, dx = r % 3 - 1;
        const unsigned short* vp = &Vh[ly + dy + 1][lx + dx + 1][hg * 16];
        short8 v8a = *(const short8*)&vp[0];
        short8 v8b = *(const short8*)&vp[8];
        #pragma unroll
        for (int j = 0; j < 8; ++j) {
            acc[j]     = fmaf(w[r], b2f((unsigned short)v8a[j]), acc[j]);
            acc[8 + j] = fmaf(w[r], b2f((unsigned short)v8b[j]), acc[8 + j]);
        }
    }

    // ---- write-out via tr[32][65], two 64-px halves (verified pattern) ----
    const int ch  = t >> 3;                   // 0..31
    const int sub = t & 7;
    const int ly2 = sub >> 1, xh = sub & 1;
    #pragma unroll
    for (int h = 0; h < 2; ++h) {
        if (h) __syncthreads();               // tr reuse protection
        if ((pxl >> 6) == h) {
            #pragma unroll
            for (int j = 0; j < 16; ++j)
                tr[hg * 16 + j][pxl & 63] = acc[j];
        }
        __syncthreads();
        float4_ o0, o1;
        #pragma unroll
        for (int j = 0; j < 4; ++j) {
            o0[j] = tr[ch][ly2 * 16 + xh * 8 + j];
            o1[j] = tr[ch][ly2 * 16 + xh * 8 + 4 + j];
        }
        float* o = out + (size_t)(head * DKH + ch) * HW_
                 + (y0 + h * 4 + ly2) * WI + x0 + xh * 8;
        *(float4_*)&o[0] = o0;
        *(float4_*)&o[4] = o1;
    }
}

// ---------------------------------------------------------------------------
// Workspace layout:
//   [0, 196608)              wqkv : 8*96*128 bf16
//   [196608, 19071104)       vbuf : 8*36864*32 bf16 (pixel-major)
//   [19071104, 20250752)     sbuf : 8*36864 fp32
// ---------------------------------------------------------------------------
extern "C" void kernel_launch(void* const* d_in, const int* in_sizes, int n_in,
                              void* d_out, int out_size, void* d_ws, size_t ws_size,
                              hipStream_t stream) {
    const float* x  = (const float*)d_in[0];
    const float* wq = (const float*)d_in[1];
    const float* wk = (const float*)d_in[2];
    const float* wv = (const float*)d_in[3];

    char* ws = (char*)d_ws;
    unsigned short* wqkv = (unsigned short*)ws;
    unsigned short* vbuf = (unsigned short*)(ws + 196608);
    float*          sbuf = (float*)(ws + 19071104);

    convw_kernel<<<384, 256, 0, stream>>>(wq, wk, wv, wqkv);
    projfused3_kernel<<<576, 256, 0, stream>>>(x, wqkv, vbuf, sbuf);
    attn_kernel<<<2304, 256, 0, stream>>>(vbuf, sbuf, (float*)d_out);
}